// Round 11
// baseline (668.788 us; speedup 1.0000x reference)
//
#include <hip/hip_runtime.h>
#include <math.h>

#define NB 4
#define NW 24
#define H 512
#define H2 1024
#define H5 2560
#define NCELL 300   // n*(n+1)/2 valid cells per batch
#define NEED_BYTES ((size_t)80<<20)

// Private fallback workspace: allocated ONCE at library load (outside
// kernel_launch, so graph capture never sees the hipMalloc).
static float* g_buf = nullptr;
__attribute__((constructor)) static void dio_alloc_ws(){
  (void)hipMalloc((void**)&g_buf, NEED_BYTES);
}

typedef __attribute__((ext_vector_type(8))) short bf16x8;   // 8 bf16 (4 VGPRs)
typedef __attribute__((ext_vector_type(4))) float f32x4;
typedef unsigned short ushort_t;

__device__ __forceinline__ int coff(int l){ return l*NW - (l*(l-1))/2; }
__device__ __forceinline__ float sigm(float x){ return 1.f/(1.f+__expf(-x)); }
__device__ __forceinline__ float ftanh(float x){ return 1.f - 2.f/(__expf(2.f*x)+1.f); }

__device__ __forceinline__ ushort_t f2b(float x){  // fp32 -> bf16 RNE
  unsigned int u = __float_as_uint(x);
  u += 0x7FFF + ((u>>16)&1);
  return (ushort_t)(u>>16);
}
__device__ __forceinline__ float b2f(ushort_t h){
  return __uint_as_float(((unsigned int)h)<<16);
}
// split-bf16: x ~= hi + lo with effective ~2^-17 relative error
__device__ __forceinline__ void split_store(ushort_t* __restrict__ ph,
                                            ushort_t* __restrict__ pl,
                                            size_t idx, float x){
  ushort_t h = f2b(x);
  ph[idx] = h;
  pl[idx] = f2b(x - b2f(h));
}

// agent-scope (MALL) primitives — validated bit-exact channel (rounds 3,6):
// producer agent stores + vmcnt drain (via __syncthreads) + counter RMW;
// consumer: single-lane counter spin + PLAIN cached loads of write-once lines.
__device__ __forceinline__ unsigned ldA(const unsigned* p){
  return __hip_atomic_load(p, __ATOMIC_RELAXED, __HIP_MEMORY_SCOPE_AGENT);
}
__device__ __forceinline__ unsigned addA(unsigned* p, unsigned v){
  return __hip_atomic_fetch_add(p, v, __ATOMIC_RELAXED, __HIP_MEMORY_SCOPE_AGENT);
}
__device__ __forceinline__ void stAu(unsigned* p, unsigned v){
  __hip_atomic_store(p, v, __ATOMIC_RELAXED, __HIP_MEMORY_SCOPE_AGENT);
}

// async global->LDS copy, 16B per lane (dwordx4).
__device__ __forceinline__ void gload_lds16(const void* g, void* l){
  __builtin_amdgcn_global_load_lds(
      (const __attribute__((address_space(1))) unsigned int*)g,
      (__attribute__((address_space(3))) unsigned int*)l, 16, 0, 0);
}

// full-wave dot: compat(lc,rc) = U[lc].[H(rc);C(rc)] + S[lc] + S[rc]
__device__ __forceinline__ float compat_dot(const float* __restrict__ cU,
                                            const float* __restrict__ cH,
                                            const float* __restrict__ cC,
                                            const float* __restrict__ cS,
                                            int lc, int rc, int lane){
  const float4* U4  = (const float4*)(cU + (size_t)lc*H2);
  const float4* Hr4 = (const float4*)(cH + (size_t)rc*H);
  const float4* Cr4 = (const float4*)(cC + (size_t)rc*H);
  float p = 0.f;
  #pragma unroll
  for (int it=0; it<2; it++){
    float4 u = U4[lane + 64*it], h = Hr4[lane + 64*it];
    p += u.x*h.x + u.y*h.y + u.z*h.z + u.w*h.w;
  }
  #pragma unroll
  for (int it=0; it<2; it++){
    float4 u = U4[128 + lane + 64*it], c = Cr4[lane + 64*it];
    p += u.x*c.x + u.y*c.y + u.z*c.z + u.w*c.w;
  }
  #pragma unroll
  for (int off=32; off>0; off>>=1) p += __shfl_down(p, off);
  return p + cS[lc] + cS[rc];
}

// ---- merged init: weight blobs (pre-swizzled LDS images), leaves, counters.
__global__ void k_init(const float* __restrict__ seqt,
                       const float* __restrict__ Wi, const float* __restrict__ Ws,
                       const float* __restrict__ Wbil,
                       ushort_t* __restrict__ WWblob, ushort_t* __restrict__ WBblob,
                       float* __restrict__ cH, float* __restrict__ cC, float* __restrict__ cS,
                       ushort_t* __restrict__ cHbh, ushort_t* __restrict__ cHbl,
                       ushort_t* __restrict__ cCbh, ushort_t* __restrict__ cCbl,
                       unsigned* __restrict__ ctr){
  const int blk = blockIdx.x, t = threadIdx.x;
  if (blk < 1280){                        // Wi/Ws -> WWblob (8-elem chunks)
    const int gid = blk*256 + t;          // 327680 chunks total
    const int half = 163840;
    const float* mat = (gid < half) ? Wi : Ws;
    const int cid = (gid < half) ? gid : gid - half;
    const int j = cid >> 6;               // row 0..2559
    const int c0 = (cid & 63) << 3;       // col chunk base
    const int tile = ((gid < half) ? 0 : 160) + (j >> 4);
    const int row = j & 15;
    const float4* s = (const float4*)(mat + (size_t)j*H + c0);
    float4 a = s[0], b4 = s[1];
    float xs[8] = {a.x,a.y,a.z,a.w, b4.x,b4.y,b4.z,b4.w};
    union { ushort_t u[8]; bf16x8 v; } hh, ll;
    #pragma unroll
    for (int i=0;i<8;i++){
      ushort_t h = f2b(xs[i]);
      hh.u[i] = h; ll.u[i] = f2b(xs[i] - b2f(h));
    }
    char* base = (char*)WWblob + (size_t)tile*32768;
    const int off = ((row<<10) + (c0<<1)) ^ ((row&7)<<4);
    *(bf16x8*)(base + off) = hh.v;
    *(bf16x8*)(base + 16384 + off) = ll.v;
  } else if (blk < 2304){                 // Wbil transpose -> WBblob (1024 tiles)
    __shared__ float tile[32][33];
    int tb = blk - 1280;
    int tr = (tb>>5)*32, tc = (tb&31)*32;
    int tx = t & 31, ty = t >> 5;         // 32 x 8
    #pragma unroll
    for (int i=0;i<32;i+=8)
      tile[ty+i][tx] = Wbil[(size_t)(tr+ty+i)*H2 + tc+tx];
    __syncthreads();
    if (t < 128){                         // 32 cols x 4 k-chunks of 8
      const int c = t & 31, r0 = (t >> 5) << 3;
      const int jg = tc + c;              // output row (Wbil column)
      const int k0 = tr + r0;             // output k-chunk base
      union { ushort_t u[8]; bf16x8 v; } hh, ll;
      #pragma unroll
      for (int i=0;i<8;i++){
        float x = tile[r0+i][c];
        ushort_t h = f2b(x);
        hh.u[i] = h; ll.u[i] = f2b(x - b2f(h));
      }
      char* base = (char*)WBblob + (size_t)(jg>>4)*65536;
      const int row = jg & 15;
      const int off = ((row<<11) + (k0<<1)) ^ ((row&7)<<4);
      *(bf16x8*)(base + off) = hh.v;
      *(bf16x8*)(base + 32768 + off) = ll.v;
    }
  } else if (blk < 2496){                 // leaves (192 blocks)
    int tid = (blk-2304)*256 + t;
    if (tid < NB*NW*H){
      int b = tid/(NW*H); int r = tid%(NW*H); int i = r/H; int d = r%H;
      size_t idx = (size_t)(b*NCELL + i)*H + d;     // coff(0)==0
      float hv = seqt[(size_t)(b*NW+i)*H2 + d];
      float cv = seqt[(size_t)(b*NW+i)*H2 + H + d];
      cH[idx]=hv; cC[idx]=cv;
      split_store(cHbh,cHbl,idx,hv);
      split_store(cCbh,cCbl,idx,cv);
      if (d==0) cS[b*NCELL+i] = 0.f;
    }
  } else {                                // per-stage chunk counters
    for (int i=t; i<NW*64; i+=256) ctr[i] = 0u;
  }
}

__device__ __forceinline__ void mfma3(f32x4& acc, bf16x8 ah, bf16x8 al,
                                      bf16x8 bh, bf16x8 bl){
  // split product; lo*lo (~2^-34 rel) dropped
  acc = __builtin_amdgcn_mfma_f32_16x16x32_bf16(ah, bh, acc, 0,0,0);
  acc = __builtin_amdgcn_mfma_f32_16x16x32_bf16(ah, bl, acc, 0,0,0);
  acc = __builtin_amdgcn_mfma_f32_16x16x32_bf16(al, bh, acc, 0,0,0);
}

// ---- fused stage L: D_L = {combine(L), proj(L), gates(L+1), writers(L+1)}.
// Same-dispatch edge ONLY combine->proj bf16 charts (agent stores ->
// chunk counter -> single-lane spin -> PLAIN loads). Everything else is
// prev-dispatch plain. gH/gM and compat are parity-double-buffered so the
// same-dispatch gate/writer writes never alias combine's reads.
// Deadlock-free by capacity: proj<=384 blocks occupy <=192 CUs (2/CU at
// 72.6KB LDS); >=128 free slots >= ncomb<=92 spin-free combine blocks.
__global__ void __launch_bounds__(512)
k_stageF(const ushort_t* __restrict__ WWblob, const ushort_t* __restrict__ WBblob,
         const float* __restrict__ bi, const float* __restrict__ bs,
         ushort_t* __restrict__ cHbh, ushort_t* __restrict__ cHbl,
         ushort_t* __restrict__ cCbh, ushort_t* __restrict__ cCbl,
         float* __restrict__ cPI, float* __restrict__ cPS, float* __restrict__ cU,
         float* __restrict__ cH, float* __restrict__ cC, float* __restrict__ cS,
         const float* __restrict__ compatR, float* __restrict__ compatW,
         const float* __restrict__ gHr, const float* __restrict__ gMr,
         float* __restrict__ gHw, float* __restrict__ gMw,
         unsigned* __restrict__ ctrL, float* __restrict__ out, int L, int P)
{
  __shared__ __attribute__((aligned(16))) ushort_t wlds[32768];  // 64 KB
  __shared__ f32x4 red[8][64];                                   // 8 KB
  __shared__ float compat_s[32];
  __shared__ float wts_s[32];
  __shared__ float S_s;

  const int t = threadIdx.x, wv = t>>6, lane = t&63;
  const int Mtot = NB*P;
  const int ncomb = (L>=1) ? Mtot : 0;
  const int nproj = (L<=NW-2) ? 384 : 0;
  const int nk = L-1;                    // interior splits of diag L+1
  const int Pg = NW-L-1;
  const int ngate = (nproj && nk>=1) ? NB*Pg*nk : 0;
  int blk = blockIdx.x;

  // ============ role A: combine one cell of diagonal L (L>=1) ============
  if (blk < ncomb){
    const int b = blk / P, left = blk % P;
    // phase 1: boundary compat inline (waves 4,5); interior precomputed
    if (wv == 4){
      int lc = b*NCELL + left;                       // (left,0) leaf
      int rc = b*NCELL + coff(L-1) + left+1;
      float v = compat_dot(cU, cH, cC, cS, lc, rc, lane);
      if (lane==0) compat_s[0] = v;
    } else if (wv == 5 && L >= 2){
      int lc = b*NCELL + coff(L-1) + left;
      int rc = b*NCELL + left+L;                     // (left+L,0) leaf
      float v = compat_dot(cU, cH, cC, cS, lc, rc, lane);
      if (lane==0) compat_s[L-1] = v;
    }
    if (t >= 1 && t <= L-2) compat_s[t] = compatR[(b*NW + left)*NW + t];
    __syncthreads();
    const size_t nc = (size_t)(b*NCELL + coff(L) + left);
    // phase 2: softmax over k (serial on t0, order-identical)
    if (t==0){
      float mx = -1e30f;
      for (int k=0;k<L;k++) mx = fmaxf(mx, compat_s[k]);
      float den = 0.f;
      for (int k=0;k<L;k++){ float e = __expf(compat_s[k]-mx); wts_s[k]=e; den+=e; }
      float inv = 1.f/den, S = 0.f;
      for (int k=0;k<L;k++){ wts_s[k]*=inv; S += wts_s[k]*compat_s[k]; }
      if (L < NW-1) cS[nc] = S;
    }
    __syncthreads();
    // phase 3: dim=t; q8 residue partials summed sequentially (bit-exact
    // association, validated r9). Interior from gHr/gMr; boundary inline.
    const int dim = t;
    float aH = 0.f, aC = 0.f;
    for (int q8=0; q8<8; q8++){
      float sH = 0.f, sC = 0.f;
      for (int k=q8; k<L; k+=8){
        float wk = wts_s[k];
        float mem, h;
        if (k == 0 || k == L-1){
          int lc = b*NCELL + coff(k) + left;
          int rc = b*NCELL + coff(L-1-k) + left+k+1;
          const float* PI = cPI + (size_t)lc*H5;
          const float* PS = cPS + (size_t)rc*H5;
          float p0 = PI[dim]     + PS[dim];
          float p1 = PI[H+dim]   + PS[H+dim];
          float p2 = PI[2*H+dim] + PS[2*H+dim];
          float p3 = PI[3*H+dim] + PS[3*H+dim];
          float p4 = PI[4*H+dim] + PS[4*H+dim];
          float lcv = cC[(size_t)lc*H + dim];
          float rcv = cC[(size_t)rc*H + dim];
          mem = sigm(p1)*lcv + sigm(p2)*rcv + sigm(p0)*ftanh(p3);
          h = sigm(p4)*ftanh(mem);
        } else {
          const size_t gidx = ((size_t)(b*NW + left)*NW + k)*H + dim;
          h = gHr[gidx];
          mem = gMr[gidx];
        }
        sH += wk*h; sC += wk*mem;
      }
      aH += sH; aC += sC;
    }
    if (L == NW-1){                        // root: write output directly
      out[b*H2 + dim]     = aH;
      out[b*H2 + H + dim] = aC;
      return;
    }
    cH[nc*H + dim] = aH;                   // plain: consumed next dispatch
    cC[nc*H + dim] = aC;
    // bf16 splits for SAME-dispatch proj: packed agent stores (r3 channel)
    ushort_t hH = f2b(aH), lH = f2b(aH - b2f(hH));
    ushort_t hC = f2b(aC), lC = f2b(aC - b2f(hC));
    unsigned nh = (unsigned)__shfl_down((int)hH, 1);
    unsigned nl = (unsigned)__shfl_down((int)lH, 1);
    unsigned mh = (unsigned)__shfl_down((int)hC, 1);
    unsigned ml = (unsigned)__shfl_down((int)lC, 1);
    if (!(t & 1)){
      const size_t pi = (nc*H + dim) >> 1;
      stAu((unsigned*)cHbh + pi, (unsigned)hH | (nh<<16));
      stAu((unsigned*)cHbl + pi, (unsigned)lH | (nl<<16));
      stAu((unsigned*)cCbh + pi, (unsigned)hC | (mh<<16));
      stAu((unsigned*)cCbl + pi, (unsigned)lC | (ml<<16));
    }
    __syncthreads();      // each wave's vmcnt drained before barrier release
    if (t == 0) addA(ctrL + ((blk>>6)<<5), 1u);   // chunk counter (128B apart)
    return;
  }
  blk -= ncomb;

  // ============ roles C/D: gates + writers for diag L+1 (no sync) ==========
  if (blk >= nproj){
    const int gi = blk - nproj;
    if (gi < ngate){
      // gate: interior (h,mem) for diag Ln=L+1; reads diags <= L-1 only
      const int Ln = L + 1;
      const int b = gi / (Pg*nk), rr = gi % (Pg*nk);
      const int left = rr / nk;
      const int k = 1 + rr % nk;
      const int lc = b*NCELL + coff(k) + left;
      const int rc = b*NCELL + coff(Ln-1-k) + left+k+1;
      const float* PI = cPI + (size_t)lc*H5;
      const float* PS = cPS + (size_t)rc*H5;
      const int dim = t;
      float p0 = PI[dim]     + PS[dim];
      float p1 = PI[H+dim]   + PS[H+dim];
      float p2 = PI[2*H+dim] + PS[2*H+dim];
      float p3 = PI[3*H+dim] + PS[3*H+dim];
      float p4 = PI[4*H+dim] + PS[4*H+dim];
      float lcv = cC[(size_t)lc*H + dim];
      float rcv = cC[(size_t)rc*H + dim];
      float mem = sigm(p1)*lcv + sigm(p2)*rcv + sigm(p0)*ftanh(p3);
      float h = sigm(p4)*ftanh(mem);
      const size_t gidx = ((size_t)(b*NW + left)*NW + k)*H + dim;
      gHw[gidx] = h;
      gMw[gidx] = mem;
    } else {
      // writer: compat interior term for diag Ln=L+1 (one item per wave)
      const int Ln = L + 1;
      const int tid8 = (gi - ngate)*8 + wv;
      if (tid8 < NB*Pg*nk){
        const int cell1 = tid8 / nk;
        const int k = 1 + tid8 % nk;
        const int b = cell1 / Pg, left = cell1 % Pg;
        const int lc = b*NCELL + coff(k) + left;
        const int rc = b*NCELL + coff(Ln-1-k) + left+k+1;
        float v = compat_dot(cU, cH, cC, cS, lc, rc, lane);
        if (lane==0) compatW[(b*NW + left)*NW + k] = v;
      }
    }
    return;
  }

  // ================== role B: proj of diagonal L ==========================
  const int jt = blk;
  const int r = lane & 15;   // A row (m) / B row (j) / D col
  const int q = lane >> 4;   // quad: k = q*8 + i

  int kind, j0;
  if (jt < 160){ kind=0; j0 = jt*16; }
  else if (jt < 320){ kind=1; j0 = (jt-160)*16; }
  else { kind=2; j0 = (jt-320)*16; }

  // stage weights into LDS (before the gate -> overlaps combine compute)
  {
    const char* blob = (kind < 2)
        ? (const char*)WWblob + (size_t)jt*32768
        : (const char*)WBblob + (size_t)(jt-320)*65536;
    const int nseg = (kind < 2) ? 4 : 8;          // 8KB segments
    for (int i = 0; i < nseg; i++){
      const int lo = i*8192 + wv*1024;
      gload_lds16(blob + lo + lane*16, (char*)wlds + lo);
    }
    asm volatile("s_waitcnt vmcnt(0)" ::: "memory");
  }
  __syncthreads();

  const int mt = (Mtot+15)>>4;
  const int swz = (r&7)<<4;
  const char* wb = (const char*)wlds;
  const int jo = j0 + r;
  float bias = 0.f;
  if (kind==0) bias = bi[jo] + ((jo>=H && jo<3*H)?1.f:0.f);   // ins_bias [H,3H)
  else if (kind==1) bias = bs[jo];

  const f32x4 z4 = {0.f,0.f,0.f,0.f};
  const int units = 2*mt;                 // (m-tile, K-half) pairs
  const int rounds = (units + 7) >> 3;
  for (int rd = 0; rd < rounds; rd++){
    // gate: wait for this round's 64-cell chunk of same-dispatch combine
    if (ncomb > 0){
      if (t == 0){
        const int c0 = rd*64;
        const unsigned tgt = (unsigned)((Mtot - c0 < 64) ? (Mtot - c0) : 64);
        while (ldA(ctrL + (rd<<5)) < tgt) __builtin_amdgcn_s_sleep(8);
      }
      __syncthreads();
    }
    const int u = rd*8 + wv;
    const int half = u & 1;               // wv parity (rd*8 even)
    const int mtile = u >> 1;
    f32x4 sA = z4;
    int m0 = 0, nm = 0;
    if (u < units){
      m0 = mtile*16;
      nm = min(16, Mtot - m0);
      const int mg = m0 + (r < nm ? r : 0);
      const size_t arow = (size_t)((mg/P)*NCELL + coff(L) + mg%P)*H;
      f32x4 acc[4];
      #pragma unroll
      for (int wi=0;wi<4;wi++) acc[wi] = z4;
      if (kind < 2){
        #pragma unroll
        for (int wi=0; wi<4; wi++){
          const int w = half*4 + wi;      // chain id 0..7
          #pragma unroll
          for (int s=0;s<2;s++){
            const int ko = w*64 + q*8 + s*32;
            bf16x8 ah = *(const bf16x8*)(cHbh + arow + ko);
            bf16x8 al = *(const bf16x8*)(cHbl + arow + ko);
            const int bo = ((r<<10) + (ko<<1)) ^ swz;
            bf16x8 bh = *(const bf16x8*)(wb + bo);
            bf16x8 bl = *(const bf16x8*)(wb + 16384 + bo);
            mfma3(acc[wi], ah, al, bh, bl);
          }
        }
      } else {
        // U: chains 0-3 -> H chart, 4-7 -> C chart; global k = w*128 + ...
        const ushort_t* ah_ = (half==0 ? cHbh : cCbh) + arow;
        const ushort_t* al_ = (half==0 ? cHbl : cCbl) + arow;
        #pragma unroll
        for (int wi=0; wi<4; wi++){
          const int w = half*4 + wi;
          const int kg0 = w*128, ka0 = kg0 & 511;
          #pragma unroll
          for (int s=0;s<4;s++){
            const int so = s*32 + q*8;
            bf16x8 ah = *(const bf16x8*)(ah_ + ka0 + so);
            bf16x8 al = *(const bf16x8*)(al_ + ka0 + so);
            const int bo = ((r<<11) + ((kg0+so)<<1)) ^ swz;
            bf16x8 bh = *(const bf16x8*)(wb + bo);
            bf16x8 bl = *(const bf16x8*)(wb + 32768 + bo);
            mfma3(acc[wi], ah, al, bh, bl);
          }
        }
      }
      sA = (acc[0]+acc[1]) + (acc[2]+acc[3]);   // half-subtree, fixed order
    }
    red[wv][lane] = sA;
    __syncthreads();
    if (half==0 && u < units){
      f32x4 tot = red[wv][lane] + red[wv|1][lane];   // ((0+1)+(2+3))+((4+5)+(6+7))
      #pragma unroll
      for (int reg=0; reg<4; reg++){
        const int m = q*4 + reg;
        if (m < nm){
          const int mg2 = m0 + m;
          const size_t cell = (size_t)((mg2/P)*NCELL + coff(L) + mg2%P);
          const float v = tot[reg];
          if (kind==0)      cPI[cell*H5 + jo] = v + bias;   // plain
          else if (kind==1) cPS[cell*H5 + jo] = v + bias;
          else              cU [cell*H2 + jo] = v;
        }
      }
    }
    __syncthreads();   // red reused next round
  }
}

extern "C" void kernel_launch(void* const* d_in, const int* in_sizes, int n_in,
                              void* d_out, int out_size, void* d_ws, size_t ws_size,
                              hipStream_t stream){
  const float* seqt = (const float*)d_in[0];
  const float* Wi   = (const float*)d_in[1];
  const float* bi   = (const float*)d_in[2];
  const float* Ws   = (const float*)d_in[3];
  const float* bs   = (const float*)d_in[4];
  const float* Wbil = (const float*)d_in[5];
  float* out = (float*)d_out;

  float* p = (ws_size >= NEED_BYTES && g_buf == nullptr) ? (float*)d_ws : g_buf;
  float* cH  = p; p += (size_t)NB*NCELL*H;
  float* cC  = p; p += (size_t)NB*NCELL*H;
  float* cS  = p; p += (size_t)NB*NCELL;
  float* cPI = p; p += (size_t)NB*NCELL*H5;
  float* cPS = p; p += (size_t)NB*NCELL*H5;
  float* cU  = p; p += (size_t)NB*NCELL*H2;
  float* compatA = p; p += (size_t)NB*NW*NW;
  float* compatB = p; p += (size_t)NB*NW*NW;
  float* gHa = p; p += (size_t)NB*NW*NW*H;   // gate buffers, parity 1 (odd L)
  float* gMa = p; p += (size_t)NB*NW*NW*H;
  float* gHb = p; p += (size_t)NB*NW*NW*H;   // parity 0 (even L)
  float* gMb = p; p += (size_t)NB*NW*NW*H;
  ushort_t* u = (ushort_t*)p;
  ushort_t* WWblob = u; u += (size_t)320*16384;   // 320 x 32KB LDS images
  ushort_t* WBblob = u; u += (size_t)64*32768;    // 64 x 64KB LDS images
  ushort_t* cHbh   = u; u += (size_t)NB*NCELL*H;
  ushort_t* cHbl   = u; u += (size_t)NB*NCELL*H;
  ushort_t* cCbh   = u; u += (size_t)NB*NCELL*H;
  ushort_t* cCbl   = u; u += (size_t)NB*NCELL*H;
  unsigned* ctr    = (unsigned*)u;   // NW*64 u32 chunk counters

  k_init<<<2497, 256, 0, stream>>>(seqt, Wi, Ws, Wbil,
      WWblob, WBblob, cH, cC, cS, cHbh, cHbl, cCbh, cCbl, ctr);

  for (int L = 0; L < NW; L++){
    const int P = NW - L;
    const int ncomb = (L>=1) ? NB*P : 0;
    const int nproj = (L<=NW-2) ? 384 : 0;
    const int Ln = L + 1, nk = L - 1, Pg = NW - Ln;
    const int ngate = (nproj && nk>=1) ? NB*Pg*nk : 0;
    const int wblk  = (nproj && nk>=1) ? (NB*Pg*nk + 7)/8 : 0;
    float* bufR = (L&1)  ? compatA : compatB;
    float* bufW = (Ln&1) ? compatA : compatB;
    const float* gHr = (L&1)  ? gHa : gHb;
    const float* gMr = (L&1)  ? gMa : gMb;
    float* gHw = (Ln&1) ? gHa : gHb;
    float* gMw = (Ln&1) ? gMa : gMb;
    k_stageF<<<ncomb + nproj + ngate + wblk, 512, 0, stream>>>(
        WWblob, WBblob, bi, bs,
        cHbh, cHbl, cCbh, cCbl, cPI, cPS, cU, cH, cC, cS,
        bufR, bufW, gHr, gMr, gHw, gMw, ctr + L*64, out, L, P);
  }
}

// Round 12
// 564.468 us; speedup vs baseline: 1.1848x; 1.1848x over previous
//
#include <hip/hip_runtime.h>
#include <math.h>

#define NB 4
#define NW 24
#define H 512
#define H2 1024
#define H5 2560
#define NCELL 300   // n*(n+1)/2 valid cells per batch
#define NEED_BYTES ((size_t)72<<20)

// Private fallback workspace: allocated ONCE at library load (outside
// kernel_launch, so graph capture never sees the hipMalloc).
static float* g_buf = nullptr;
__attribute__((constructor)) static void dio_alloc_ws(){
  (void)hipMalloc((void**)&g_buf, NEED_BYTES);
}

typedef __attribute__((ext_vector_type(8))) short bf16x8;   // 8 bf16 (4 VGPRs)
typedef __attribute__((ext_vector_type(4))) float f32x4;
typedef unsigned short ushort_t;

__device__ __forceinline__ int coff(int l){ return l*NW - (l*(l-1))/2; }
__device__ __forceinline__ float sigm(float x){ return 1.f/(1.f+__expf(-x)); }
__device__ __forceinline__ float ftanh(float x){ return 1.f - 2.f/(__expf(2.f*x)+1.f); }

__device__ __forceinline__ ushort_t f2b(float x){  // fp32 -> bf16 RNE
  unsigned int u = __float_as_uint(x);
  u += 0x7FFF + ((u>>16)&1);
  return (ushort_t)(u>>16);
}
__device__ __forceinline__ float b2f(ushort_t h){
  return __uint_as_float(((unsigned int)h)<<16);
}
// split-bf16: x ~= hi + lo with effective ~2^-17 relative error
__device__ __forceinline__ void split_store(ushort_t* __restrict__ ph,
                                            ushort_t* __restrict__ pl,
                                            size_t idx, float x){
  ushort_t h = f2b(x);
  ph[idx] = h;
  pl[idx] = f2b(x - b2f(h));
}

// async global->LDS copy, 16B per lane (dwordx4). LDS dest = uniform base +
// lane*16 (HW rule, learn_hip m104); global src is per-lane.
__device__ __forceinline__ void gload_lds16(const void* g, void* l){
  __builtin_amdgcn_global_load_lds(
      (const __attribute__((address_space(1))) unsigned int*)g,
      (__attribute__((address_space(3))) unsigned int*)l, 16, 0, 0);
}

// full-wave dot: compat(lc,rc) = U[lc].[H(rc);C(rc)] + S[lc] + S[rc]
__device__ __forceinline__ float compat_dot(const float* __restrict__ cU,
                                            const float* __restrict__ cH,
                                            const float* __restrict__ cC,
                                            const float* __restrict__ cS,
                                            int lc, int rc, int lane){
  const float4* U4  = (const float4*)(cU + (size_t)lc*H2);
  const float4* Hr4 = (const float4*)(cH + (size_t)rc*H);
  const float4* Cr4 = (const float4*)(cC + (size_t)rc*H);
  float p = 0.f;
  #pragma unroll
  for (int it=0; it<2; it++){
    float4 u = U4[lane + 64*it], h = Hr4[lane + 64*it];
    p += u.x*h.x + u.y*h.y + u.z*h.z + u.w*h.w;
  }
  #pragma unroll
  for (int it=0; it<2; it++){
    float4 u = U4[128 + lane + 64*it], c = Cr4[lane + 64*it];
    p += u.x*c.x + u.y*c.y + u.z*c.z + u.w*c.w;
  }
  #pragma unroll
  for (int off=32; off>0; off>>=1) p += __shfl_down(p, off);
  return p + cS[lc] + cS[rc];
}

// ---- merged init: weight blobs (pre-swizzled LDS images), leaves.
__global__ void k_init(const float* __restrict__ seqt,
                       const float* __restrict__ Wi, const float* __restrict__ Ws,
                       const float* __restrict__ Wbil,
                       ushort_t* __restrict__ WWblob, ushort_t* __restrict__ WBblob,
                       float* __restrict__ cH, float* __restrict__ cC, float* __restrict__ cS,
                       ushort_t* __restrict__ cHbh, ushort_t* __restrict__ cHbl,
                       ushort_t* __restrict__ cCbh, ushort_t* __restrict__ cCbl){
  const int blk = blockIdx.x, t = threadIdx.x;
  if (blk < 1280){                        // Wi/Ws -> WWblob (8-elem chunks)
    const int gid = blk*256 + t;          // 327680 chunks total
    const int half = 163840;
    const float* mat = (gid < half) ? Wi : Ws;
    const int cid = (gid < half) ? gid : gid - half;
    const int j = cid >> 6;               // row 0..2559
    const int c0 = (cid & 63) << 3;       // col chunk base
    const int tile = ((gid < half) ? 0 : 160) + (j >> 4);
    const int row = j & 15;
    const float4* s = (const float4*)(mat + (size_t)j*H + c0);
    float4 a = s[0], b4 = s[1];
    float xs[8] = {a.x,a.y,a.z,a.w, b4.x,b4.y,b4.z,b4.w};
    union { ushort_t u[8]; bf16x8 v; } hh, ll;
    #pragma unroll
    for (int i=0;i<8;i++){
      ushort_t h = f2b(xs[i]);
      hh.u[i] = h; ll.u[i] = f2b(xs[i] - b2f(h));
    }
    char* base = (char*)WWblob + (size_t)tile*32768;
    const int off = ((row<<10) + (c0<<1)) ^ ((row&7)<<4);
    *(bf16x8*)(base + off) = hh.v;
    *(bf16x8*)(base + 16384 + off) = ll.v;
  } else if (blk < 2304){                 // Wbil transpose -> WBblob (1024 tiles)
    __shared__ float tile[32][33];
    int tb = blk - 1280;
    int tr = (tb>>5)*32, tc = (tb&31)*32;
    int tx = t & 31, ty = t >> 5;         // 32 x 8
    #pragma unroll
    for (int i=0;i<32;i+=8)
      tile[ty+i][tx] = Wbil[(size_t)(tr+ty+i)*H2 + tc+tx];
    __syncthreads();
    if (t < 128){                         // 32 cols x 4 k-chunks of 8
      const int c = t & 31, r0 = (t >> 5) << 3;
      const int jg = tc + c;              // output row (Wbil column)
      const int k0 = tr + r0;             // output k-chunk base
      union { ushort_t u[8]; bf16x8 v; } hh, ll;
      #pragma unroll
      for (int i=0;i<8;i++){
        float x = tile[r0+i][c];
        ushort_t h = f2b(x);
        hh.u[i] = h; ll.u[i] = f2b(x - b2f(h));
      }
      char* base = (char*)WBblob + (size_t)(jg>>4)*65536;
      const int row = jg & 15;
      const int off = ((row<<11) + (k0<<1)) ^ ((row&7)<<4);
      *(bf16x8*)(base + off) = hh.v;
      *(bf16x8*)(base + 32768 + off) = ll.v;
    }
  } else {                                // leaves (192 blocks)
    int tid = (blk-2304)*256 + t;
    if (tid < NB*NW*H){
      int b = tid/(NW*H); int r = tid%(NW*H); int i = r/H; int d = r%H;
      size_t idx = (size_t)(b*NCELL + i)*H + d;     // coff(0)==0
      float hv = seqt[(size_t)(b*NW+i)*H2 + d];
      float cv = seqt[(size_t)(b*NW+i)*H2 + H + d];
      cH[idx]=hv; cC[idx]=cv;
      split_store(cHbh,cHbl,idx,hv);
      split_store(cCbh,cCbl,idx,cv);
      if (d==0) cS[b*NCELL+i] = 0.f;
    }
  }
}

__device__ __forceinline__ void mfma3(f32x4& acc, bf16x8 ah, bf16x8 al,
                                      bf16x8 bh, bf16x8 bl){
  // split product; lo*lo (~2^-34 rel) dropped
  acc = __builtin_amdgcn_mfma_f32_16x16x32_bf16(ah, bh, acc, 0,0,0);
  acc = __builtin_amdgcn_mfma_f32_16x16x32_bf16(ah, bl, acc, 0,0,0);
  acc = __builtin_amdgcn_mfma_f32_16x16x32_bf16(al, bh, acc, 0,0,0);
}

// ---- MFMA projections of diag d + INTERIOR-GATE precompute for diag d+1.
// Blocks [0,384): proj j-tiles (identical to round 7, bit-exact).
// Blocks [384, 384+ngate): gate blocks — one per (b,left,k-interior) of the
// NEXT diagonal Ln=d+1. They read ONLY diags <= Ln-2 (strictly older than
// anything this dispatch writes -> no sync), compute the exact combine
// mem/h expressions unweighted, store fp32 to gH/gM. Combine then reads 2
// floats instead of 12 per interior (k,dim). fp32 store/reload is exact ->
// bit-exact overall.
__global__ void __launch_bounds__(512)
k_proj4(const ushort_t* __restrict__ WWblob, const ushort_t* __restrict__ WBblob,
        const float* __restrict__ bi, const float* __restrict__ bs,
        const ushort_t* __restrict__ cHbh, const ushort_t* __restrict__ cHbl,
        const ushort_t* __restrict__ cCbh, const ushort_t* __restrict__ cCbl,
        const float* __restrict__ cC,
        float* __restrict__ cPI, float* __restrict__ cPS, float* __restrict__ cU,
        float* __restrict__ gH, float* __restrict__ gM,
        int d, int P)
{
  __shared__ __attribute__((aligned(16))) ushort_t wlds[32768];  // 64 KB
  __shared__ f32x4 red[8][64];                                   // 8 KB
  const int t = threadIdx.x, wv = t>>6, lane = t&63;
  const int jt = blockIdx.x;

  if (jt >= 384){
    // ---- gate block for diag Ln = d+1, interior split k in [1,Ln-2]
    const int Ln = d + 1;
    const int nk = Ln - 2;               // >=1 guaranteed by launcher
    const int Pg = NW - Ln;
    const int gi = jt - 384;             // < NB*Pg*nk
    const int b = gi / (Pg*nk), rr = gi % (Pg*nk);
    const int left = rr / nk;
    const int k = 1 + rr % nk;
    const int lc = b*NCELL + coff(k) + left;
    const int rc = b*NCELL + coff(Ln-1-k) + left+k+1;
    const float* PI = cPI + (size_t)lc*H5;
    const float* PS = cPS + (size_t)rc*H5;
    const int dim = t;                   // 512 threads = 512 dims
    float p0 = PI[dim]     + PS[dim];
    float p1 = PI[H+dim]   + PS[H+dim];
    float p2 = PI[2*H+dim] + PS[2*H+dim];
    float p3 = PI[3*H+dim] + PS[3*H+dim];
    float p4 = PI[4*H+dim] + PS[4*H+dim];
    float lcv = cC[(size_t)lc*H + dim];
    float rcv = cC[(size_t)rc*H + dim];
    float mem = sigm(p1)*lcv + sigm(p2)*rcv + sigm(p0)*ftanh(p3);
    float h = sigm(p4)*ftanh(mem);
    const size_t gidx = ((size_t)(b*NW + left)*NW + k)*H + dim;
    gH[gidx] = h;
    gM[gidx] = mem;
    return;
  }

  const int r = lane & 15;   // A row (m) / B row (j) / D col
  const int q = lane >> 4;   // quad: k = q*8 + i

  int kind, j0;
  if (jt < 160){ kind=0; j0 = jt*16; }
  else if (jt < 320){ kind=1; j0 = (jt-160)*16; }
  else { kind=2; j0 = (jt-320)*16; }

  // ---- stage weights into LDS: linear async copy of the blob image
  {
    const char* blob = (kind < 2)
        ? (const char*)WWblob + (size_t)jt*32768
        : (const char*)WBblob + (size_t)(jt-320)*65536;
    const int nseg = (kind < 2) ? 4 : 8;          // 8KB segments
    for (int i = 0; i < nseg; i++){
      const int lo = i*8192 + wv*1024;
      gload_lds16(blob + lo + lane*16, (char*)wlds + lo);
    }
    asm volatile("s_waitcnt vmcnt(0)" ::: "memory");
  }
  __syncthreads();

  const int Mtot = NB*P, mt = (Mtot+15)>>4;
  const int swz = (r&7)<<4;
  const char* wb = (const char*)wlds;
  const int jo = j0 + r;
  float bias = 0.f;
  if (kind==0) bias = bi[jo] + ((jo>=H && jo<3*H)?1.f:0.f);   // ins_bias on [H,3H)
  else if (kind==1) bias = bs[jo];

  const f32x4 z4 = {0.f,0.f,0.f,0.f};
  const int units = 2*mt;                 // (m-tile, K-half) pairs
  const int rounds = (units + 7) >> 3;
  for (int rd = 0; rd < rounds; rd++){
    const int u = rd*8 + wv;
    const int half = u & 1;               // wv parity (rd*8 even)
    const int mtile = u >> 1;
    f32x4 sA = z4;
    int m0 = 0, nm = 0;
    if (u < units){
      m0 = mtile*16;
      nm = min(16, Mtot - m0);
      const int mg = m0 + (r < nm ? r : 0);
      const size_t arow = (size_t)((mg/P)*NCELL + coff(d) + mg%P)*H;
      f32x4 acc[4];
      #pragma unroll
      for (int wi=0;wi<4;wi++) acc[wi] = z4;
      if (kind < 2){
        #pragma unroll
        for (int wi=0; wi<4; wi++){
          const int w = half*4 + wi;      // chain id 0..7
          #pragma unroll
          for (int s=0;s<2;s++){
            const int ko = w*64 + q*8 + s*32;
            bf16x8 ah = *(const bf16x8*)(cHbh + arow + ko);
            bf16x8 al = *(const bf16x8*)(cHbl + arow + ko);
            const int bo = ((r<<10) + (ko<<1)) ^ swz;
            bf16x8 bh = *(const bf16x8*)(wb + bo);
            bf16x8 bl = *(const bf16x8*)(wb + 16384 + bo);
            mfma3(acc[wi], ah, al, bh, bl);
          }
        }
      } else {
        // U: chains 0-3 -> H chart, 4-7 -> C chart; global k = w*128 + ...
        const ushort_t* ah_ = (half==0 ? cHbh : cCbh) + arow;
        const ushort_t* al_ = (half==0 ? cHbl : cCbl) + arow;
        #pragma unroll
        for (int wi=0; wi<4; wi++){
          const int w = half*4 + wi;
          const int kg0 = w*128, ka0 = kg0 & 511;
          #pragma unroll
          for (int s=0;s<4;s++){
            const int so = s*32 + q*8;
            bf16x8 ah = *(const bf16x8*)(ah_ + ka0 + so);
            bf16x8 al = *(const bf16x8*)(al_ + ka0 + so);
            const int bo = ((r<<11) + ((kg0+so)<<1)) ^ swz;
            bf16x8 bh = *(const bf16x8*)(wb + bo);
            bf16x8 bl = *(const bf16x8*)(wb + 32768 + bo);
            mfma3(acc[wi], ah, al, bh, bl);
          }
        }
      }
      sA = (acc[0]+acc[1]) + (acc[2]+acc[3]);   // half-subtree, fixed order
    }
    red[wv][lane] = sA;
    __syncthreads();
    if (half==0 && u < units){
      f32x4 tot = red[wv][lane] + red[wv|1][lane];   // ((0+1)+(2+3))+((4+5)+(6+7))
      #pragma unroll
      for (int reg=0; reg<4; reg++){
        const int m = q*4 + reg;
        if (m < nm){
          const int mg2 = m0 + m;
          const size_t cell = (size_t)((mg2/P)*NCELL + coff(d) + mg2%P);
          const float v = tot[reg];
          if (kind==0)      cPI[cell*H5 + jo] = v + bias;
          else if (kind==1) cPS[cell*H5 + jo] = v + bias;
          else              cU [cell*H2 + jo] = v;
        }
      }
    }
    __syncthreads();   // red reused next round
  }
}

// ---- combine diagonal L. Interior gates (k in [1,L-2]) come precomputed
// from the preceding proj dispatch (gH/gM); only boundary k=0 / k=L-1 are
// computed inline (they need diag L-1 proj, available since prev dispatch).
// Accumulation order per thread identical to round 2 -> bit-exact.
// grid.x = NB*P*16 phase blocks + ceil(NB*(P-1)*(L-1)/4) writer blocks.
__global__ void __launch_bounds__(256)
k_combine4(const float* __restrict__ cPI, const float* __restrict__ cPS,
           const float* __restrict__ cU,
           float* __restrict__ cH, float* __restrict__ cC, float* __restrict__ cS,
           ushort_t* __restrict__ cHbh, ushort_t* __restrict__ cHbl,
           ushort_t* __restrict__ cCbh, ushort_t* __restrict__ cCbl,
           const float* __restrict__ compatR, float* __restrict__ compatW,
           const float* __restrict__ gH, const float* __restrict__ gM,
           float* __restrict__ out, int L, int P){
  const int t = threadIdx.x;
  const int lane = t & 63;
  const int wave = t >> 6;
  const int nphase = NB*P*16;
  const int blk = blockIdx.x;

  if (blk >= nphase){
    // writer: one wave per (cell of diag L+1, split k in [1,L-1])
    const int P1 = P-1;
    const int nterm = L-1;
    int tid = (blk-nphase)*4 + wave;
    if (P1 > 0 && nterm > 0 && tid < NB*P1*nterm){
      int cell1 = tid / nterm;
      int k = 1 + tid % nterm;
      int b = cell1 / P1, left = cell1 % P1;
      // diag L+1 span (left): lcell=(left,k), rcell=(left+k+1, L-k)
      int lc = b*NCELL + coff(k) + left;
      int rc = b*NCELL + coff(L-k) + left+k+1;
      float v = compat_dot(cU, cH, cC, cS, lc, rc, lane);
      if (lane==0) compatW[(b*NW + left)*NW + k] = v;
    }
    return;
  }

  const int cellid = blk >> 4;
  const int dg = blk & 15;            // dim-group: dims [dg*32, dg*32+32)
  const int b = cellid / P;
  const int left = cellid % P;
  __shared__ float compat_s[32];
  __shared__ float wts_s[32];
  __shared__ float S_s;
  __shared__ float partH[8][32];
  __shared__ float partC[8][32];

  // phase 1: boundary terms inline (k=0 by wave 0, k=L-1 by wave 1);
  // interior terms from the precomputed buffer.
  if (wave == 0){
    int lc = b*NCELL + left;                       // (left,0) leaf
    int rc = b*NCELL + coff(L-1) + left+1;
    float v = compat_dot(cU, cH, cC, cS, lc, rc, lane);
    if (lane==0) compat_s[0] = v;
  } else if (wave == 1 && L >= 2){
    int lc = b*NCELL + coff(L-1) + left;
    int rc = b*NCELL + left+L;                     // (left+L,0) leaf
    float v = compat_dot(cU, cH, cC, cS, lc, rc, lane);
    if (lane==0) compat_s[L-1] = v;
  }
  if (t >= 1 && t <= L-2) compat_s[t] = compatR[(b*NW + left)*NW + t];
  __syncthreads();
  // phase 2: softmax over k (L<=23, serial on thread 0)
  if (t==0){
    float mx = -1e30f;
    for (int k=0;k<L;k++) mx = fmaxf(mx, compat_s[k]);
    float den = 0.f;
    for (int k=0;k<L;k++){ float e = __expf(compat_s[k]-mx); wts_s[k]=e; den+=e; }
    float inv = 1.f/den, S = 0.f;
    for (int k=0;k<L;k++){ wts_s[k]*=inv; S += wts_s[k]*compat_s[k]; }
    S_s = S;
  }
  __syncthreads();
  // phase 3: thread owns 1 dim; t>>5 selects k-residue (8-way split)
  const int dloc = t & 31;
  const int dim = dg*32 + dloc;
  const int kpar = t >> 5;
  float aH = 0.f, aC = 0.f;
  for (int k=kpar; k<L; k+=8){
    float wk = wts_s[k];
    float mem, h;
    if (k == 0 || k == L-1){
      int lc = b*NCELL + coff(k) + left;
      int rc = b*NCELL + coff(L-1-k) + left+k+1;
      const float* PI = cPI + (size_t)lc*H5;
      const float* PS = cPS + (size_t)rc*H5;
      float p0 = PI[dim]     + PS[dim];
      float p1 = PI[H+dim]   + PS[H+dim];
      float p2 = PI[2*H+dim] + PS[2*H+dim];
      float p3 = PI[3*H+dim] + PS[3*H+dim];
      float p4 = PI[4*H+dim] + PS[4*H+dim];
      float lcv = cC[(size_t)lc*H + dim];
      float rcv = cC[(size_t)rc*H + dim];
      mem = sigm(p1)*lcv + sigm(p2)*rcv + sigm(p0)*ftanh(p3);
      h = sigm(p4)*ftanh(mem);
    } else {
      const size_t gidx = ((size_t)(b*NW + left)*NW + k)*H + dim;
      h = gH[gidx];
      mem = gM[gidx];
    }
    aH += wk*h; aC += wk*mem;
  }
  if (kpar > 0){ partH[kpar][dloc]=aH; partC[kpar][dloc]=aC; }
  __syncthreads();
  if (kpar == 0){
    #pragma unroll
    for (int q=1;q<8;q++){ aH += partH[q][dloc]; aC += partC[q][dloc]; }
    if (L == NW-1){                       // root cell: write output directly
      out[b*H2 + dim]     = aH;
      out[b*H2 + H + dim] = aC;
      return;
    }
    size_t nc = (size_t)(b*NCELL + coff(L) + left);
    cH[nc*H + dim] = aH;
    cC[nc*H + dim] = aC;
    split_store(cHbh,cHbl, nc*H + dim, aH);
    split_store(cCbh,cCbl, nc*H + dim, aC);
    if (t==0 && dg==0) cS[nc] = S_s;
  }
}

extern "C" void kernel_launch(void* const* d_in, const int* in_sizes, int n_in,
                              void* d_out, int out_size, void* d_ws, size_t ws_size,
                              hipStream_t stream){
  const float* seqt = (const float*)d_in[0];
  const float* Wi   = (const float*)d_in[1];
  const float* bi   = (const float*)d_in[2];
  const float* Ws   = (const float*)d_in[3];
  const float* bs   = (const float*)d_in[4];
  const float* Wbil = (const float*)d_in[5];
  float* out = (float*)d_out;

  float* p = (ws_size >= NEED_BYTES && g_buf == nullptr) ? (float*)d_ws : g_buf;
  float* cH  = p; p += (size_t)NB*NCELL*H;
  float* cC  = p; p += (size_t)NB*NCELL*H;
  float* cS  = p; p += (size_t)NB*NCELL;
  float* cPI = p; p += (size_t)NB*NCELL*H5;
  float* cPS = p; p += (size_t)NB*NCELL*H5;
  float* cU  = p; p += (size_t)NB*NCELL*H2;
  float* compatA = p; p += (size_t)NB*NW*NW;
  float* compatB = p; p += (size_t)NB*NW*NW;
  float* gH  = p; p += (size_t)NB*NW*NW*H;        // interior gate h (fp32)
  float* gM  = p; p += (size_t)NB*NW*NW*H;        // interior gate mem (fp32)
  ushort_t* u = (ushort_t*)p;
  ushort_t* WWblob = u; u += (size_t)320*16384;   // 320 x 32KB LDS images
  ushort_t* WBblob = u; u += (size_t)64*32768;    // 64 x 64KB LDS images
  ushort_t* cHbh   = u; u += (size_t)NB*NCELL*H;
  ushort_t* cHbl   = u; u += (size_t)NB*NCELL*H;
  ushort_t* cCbh   = u; u += (size_t)NB*NCELL*H;
  ushort_t* cCbl   = u; u += (size_t)NB*NCELL*H;

  k_init<<<2496, 256, 0, stream>>>(seqt, Wi, Ws, Wbil,
      WWblob, WBblob, cH, cC, cS, cHbh, cHbl, cCbh, cCbl);

  // proj(0): diag 0; next diagonal Ln=1 has no interior gates
  k_proj4<<<384, 512, 0, stream>>>(
      WWblob, WBblob, bi, bs,
      cHbh, cHbl, cCbh, cCbl, cC, cPI, cPS, cU, gH, gM, 0, NW);
  for (int L=1; L<NW; L++){
    int P = NW - L;
    // writer blocks precompute compat interior terms for diagonal L+1
    int P1 = P-1, nterm = L-1;
    int wblk = (P1>0 && nterm>0) ? (NB*P1*nterm + 3)/4 : 0;
    float* bufR = (L&1) ? compatA : compatB;
    float* bufW = (L&1) ? compatB : compatA;
    k_combine4<<<NB*P*16 + wblk, 256, 0, stream>>>(
        cPI, cPS, cU, cH, cC, cS, cHbh, cHbl, cCbh, cCbl,
        bufR, bufW, gH, gM, out, L, P);
    if (L < NW-1){
      // proj(L): diag L; also precompute interior gates for diag Ln=L+1
      int Ln = L + 1;
      int ngate = (Ln >= 3) ? NB*(NW-Ln)*(Ln-2) : 0;
      k_proj4<<<384 + ngate, 512, 0, stream>>>(
          WWblob, WBblob, bi, bs,
          cHbh, cHbl, cCbh, cCbl, cC, cPI, cPS, cU, gH, gM, L, P);
    }
  }
}